// Round 7
// baseline (251.207 us; speedup 1.0000x reference)
//
#include <hip/hip_runtime.h>

constexpr int BB   = 4;
constexpr int CCH  = 256;
constexpr int IDIM = 128;
constexpr int NAa  = 4096;
constexpr int NDd  = 16384;
constexpr int PAD  = 320;                 // aug dim 257 padded to 320
constexpr float NAinv = 1.0f / 4096.0f;

typedef __bf16 bf16x8 __attribute__((ext_vector_type(8)));
typedef float  f32x4  __attribute__((ext_vector_type(4)));

__device__ inline unsigned short f2bfu(float f) {
    unsigned u = __float_as_uint(f);
    u += 0x7FFFu + ((u >> 16) & 1u);      // RNE
    return (unsigned short)(u >> 16);
}
__device__ inline float bf2f(unsigned short u) {
    return __uint_as_float((unsigned)u << 16);
}
// load 8 consecutive f32, convert to a bf16x8 fragment in-register
__device__ inline bf16x8 ld_cvt8(const float* p) {
    f32x4 a = *(const f32x4*)p;
    f32x4 b = *(const f32x4*)(p + 4);
    union { bf16x8 v; unsigned short u[8]; } t;
    t.u[0] = f2bfu(a[0]); t.u[1] = f2bfu(a[1]); t.u[2] = f2bfu(a[2]); t.u[3] = f2bfu(a[3]);
    t.u[4] = f2bfu(b[0]); t.u[5] = f2bfu(b[1]); t.u[6] = f2bfu(b[2]); t.u[7] = f2bfu(b[3]);
    return t.v;
}

// ===== K1: 800 independent blocks of 256 =====
//  [0,64):   S = bf16(A)·bf16(A)ᵀ per (b, 64x64 tile); 4-wave K-split(1024) + LDS reduce -> FINAL bf16 S
//  [64,80):  r rowsums (f32, from aim directly)
//  [80,800): Phat (256x320) / RhatT (320x320) prep — R1 body verbatim
__global__ __launch_bounds__(256) void k1(const float* __restrict__ aim,
                                          const float* __restrict__ qw,
                                          const float* __restrict__ gw,
                                          const float* __restrict__ gb,
                                          const float* __restrict__ thw,
                                          const float* __restrict__ thb,
                                          const float* __restrict__ phw,
                                          const float* __restrict__ phb,
                                          unsigned short* __restrict__ Sg,
                                          float* __restrict__ r,
                                          unsigned short* __restrict__ Ph,
                                          unsigned short* __restrict__ Rt) {
    __shared__ __align__(16) char sm[49152];      // S-blocks: 3x4096 f32 reduce buffer
    const int bx = blockIdx.x, t = threadIdx.x;

    if (bx < 64) {
        // ---- S tile: b = bx>>4, tile rem: mb,nb 64x64, full K=4096 split 4 waves ----
        const int b = bx >> 4, rem = bx & 15;
        const int mb = (rem >> 2) * 64, nbb = (rem & 3) * 64;
        const float* A = aim + (long)b * CCH * NAa;
        const int w = t >> 6, lane = t & 63, quad = lane >> 4, l16 = lane & 15;
        f32x4 acc[4][4] = {};
        for (int ks = 0; ks < 32; ++ks) {
            const int k = w * 1024 + ks * 32 + quad * 8;
            bf16x8 af[4], bfr[4];
            #pragma unroll
            for (int i = 0; i < 4; ++i) af[i]  = ld_cvt8(A + (long)(mb + i * 16 + l16) * NAa + k);
            #pragma unroll
            for (int j = 0; j < 4; ++j) bfr[j] = ld_cvt8(A + (long)(nbb + j * 16 + l16) * NAa + k);
            #pragma unroll
            for (int i = 0; i < 4; ++i)
                #pragma unroll
                for (int j = 0; j < 4; ++j)
                    acc[i][j] = __builtin_amdgcn_mfma_f32_16x16x32_bf16(af[i], bfr[j], acc[i][j], 0, 0, 0);
        }
        float* sred = (float*)sm;                 // 3 x 4096 f32
        if (w > 0) {
            #pragma unroll
            for (int i = 0; i < 4; ++i)
                #pragma unroll
                for (int j = 0; j < 4; ++j)
                    #pragma unroll
                    for (int reg = 0; reg < 4; ++reg)
                        sred[(w - 1) * 4096 + ((i * 4 + j) * 4 + reg) * 64 + lane] = acc[i][j][reg];
        }
        __syncthreads();
        if (w == 0) {
            #pragma unroll
            for (int i = 0; i < 4; ++i)
                #pragma unroll
                for (int j = 0; j < 4; ++j)
                    #pragma unroll
                    for (int reg = 0; reg < 4; ++reg) {
                        float v = acc[i][j][reg];
                        #pragma unroll
                        for (int rg = 0; rg < 3; ++rg)
                            v += sred[rg * 4096 + ((i * 4 + j) * 4 + reg) * 64 + lane];
                        Sg[(long)b * 65536 + (long)(mb + i * 16 + quad * 4 + reg) * 256 + nbb + j * 16 + l16] = f2bfu(v);
                    }
        }
    } else if (bx < 80) {
        // ---- rowsums: 64 rows per block, 16 per wave ----
        const int rid = bx - 64;
        const int w = t >> 6, lane = t & 63;
        for (int rr = 0; rr < 16; ++rr) {
            const int row = rid * 64 + w * 16 + rr;
            const float* src = aim + (long)row * NAa;
            float s = 0.f;
            #pragma unroll 4
            for (int q = 0; q < 16; ++q) {
                f32x4 v = *(const f32x4*)(src + q * 256 + lane * 4);
                s += v[0] + v[1] + v[2] + v[3];
            }
            #pragma unroll
            for (int off = 32; off > 0; off >>= 1) s += __shfl_down(s, off, 64);
            if (lane == 0) r[row] = s;
        }
    } else {
        // ---- prep (R1 k_prep verbatim) ----
        const int idx = (bx - 80) * 256 + t;
        if (idx < CCH * PAD) {
            const int o = idx / PAD, c = idx - o * PAD;
            float acc = 0.f;
            if (c <= 256) {
                for (int i = 0; i < IDIM; ++i)
                    acc += qw[o * IDIM + i] * ((c < 256) ? gw[i * CCH + c] : gb[i]);
            }
            Ph[idx] = f2bfu(acc);
        } else {
            const int id2 = idx - CCH * PAD;
            const int c2 = id2 / PAD, k = id2 - c2 * PAD;   // row c2, col k (transposed)
            float acc = 0.f;
            if (k <= 256 && c2 <= 256) {
                for (int i = 0; i < IDIM; ++i) {
                    const float av = (k < 256) ? thw[i * CCH + k] : thb[i];
                    const float bv = (c2 < 256) ? phw[i * CCH + c2] : phb[i];
                    acc += av * bv;
                }
            }
            Rt[id2] = f2bfu(acc);
        }
    }
}

// ===== K2: 16 blocks (4 m-strips x 4 b), 256 thr. Per strip:
//   M1 = Ph[strip,<256]·S (S symmetric -> B-frag reads S rows), M1 -> LDS bf16;
//   W5 = (M1·Rtᵀ + rank-1 aug terms) scaled + I; col 256 -> b5.  =====
__global__ __launch_bounds__(256) void k2(const unsigned short* __restrict__ Sg,
                                          const float* __restrict__ r,
                                          const unsigned short* __restrict__ Ph,
                                          const unsigned short* __restrict__ Rt,
                                          const float* __restrict__ qb,
                                          const float* __restrict__ gamma,
                                          const float* __restrict__ beta,
                                          const float* __restrict__ mean,
                                          const float* __restrict__ var,
                                          unsigned short* __restrict__ W5u,
                                          float* __restrict__ b5) {
    const int b = blockIdx.y, m0 = blockIdx.x * 64;
    const unsigned short* Sb = Sg + (long)b * 65536;
    const float* rb = r + b * CCH;
    const int t = threadIdx.x, w = t >> 6, lane = t & 63, quad = lane >> 4, l16 = lane & 15;
    __shared__ __align__(16) unsigned short M1[64][264];   // 33.8 KB, +8 pad -> 4-bank row skew
    __shared__ float sv1[320], sv2[64];

    // step A: sv1[c2] = sum_k<256 r[k]*Rt[c2][k];  sv2[t] = sum_j<256 Ph[m0+t][j]*r[j]
    for (int c2 = t; c2 < 320; c2 += 256) {
        float s = 0.f;
        for (int kk = 0; kk < 256; kk += 4) {
            ushort4 u = *(const ushort4*)(Rt + (long)c2 * PAD + kk);
            s += rb[kk] * bf2f(u.x) + rb[kk + 1] * bf2f(u.y) + rb[kk + 2] * bf2f(u.z) + rb[kk + 3] * bf2f(u.w);
        }
        sv1[c2] = s;
    }
    if (t < 64) {
        const int o = m0 + t;
        float s = 0.f;
        for (int kk = 0; kk < 256; kk += 4) {
            ushort4 u = *(const ushort4*)(Ph + (long)o * PAD + kk);
            s += rb[kk] * bf2f(u.x) + rb[kk + 1] * bf2f(u.y) + rb[kk + 2] * bf2f(u.z) + rb[kk + 3] * bf2f(u.w);
        }
        sv2[t] = s;
    }

    // step B: M1[o][k] = sum_j Ph[o][j]*S[j][k]; wave w owns out-cols w*64..+63 (B = S rows, symmetric)
    {
        f32x4 acc[4][4] = {};
        for (int jt = 0; jt < 256; jt += 32) {
            bf16x8 af[4], bfr[4];
            #pragma unroll
            for (int i = 0; i < 4; ++i)
                af[i] = *(const bf16x8*)(Ph + (long)(m0 + i * 16 + l16) * PAD + jt + quad * 8);
            #pragma unroll
            for (int j = 0; j < 4; ++j)
                bfr[j] = *(const bf16x8*)(Sb + (long)(w * 64 + j * 16 + l16) * 256 + jt + quad * 8);
            #pragma unroll
            for (int i = 0; i < 4; ++i)
                #pragma unroll
                for (int j = 0; j < 4; ++j)
                    acc[i][j] = __builtin_amdgcn_mfma_f32_16x16x32_bf16(af[i], bfr[j], acc[i][j], 0, 0, 0);
        }
        #pragma unroll
        for (int i = 0; i < 4; ++i)
            #pragma unroll
            for (int j = 0; j < 4; ++j)
                #pragma unroll
                for (int reg = 0; reg < 4; ++reg)
                    M1[i * 16 + quad * 4 + reg][w * 64 + j * 16 + l16] = f2bfu(acc[i][j][reg]);
    }
    __syncthreads();

    // step C: W5[o][c2] = sum_k M1[o][k]*Rt[c2][k] + aug; wave w owns c2 = w*80..+79
    f32x4 acc[4][5] = {};
    for (int kt = 0; kt < 256; kt += 32) {
        bf16x8 af[4], bfr[5];
        #pragma unroll
        for (int i = 0; i < 4; ++i)
            af[i] = *(const bf16x8*)&M1[i * 16 + l16][kt + quad * 8];
        #pragma unroll
        for (int j = 0; j < 5; ++j)
            bfr[j] = *(const bf16x8*)(Rt + (long)(w * 80 + j * 16 + l16) * PAD + kt + quad * 8);
        #pragma unroll
        for (int i = 0; i < 4; ++i)
            #pragma unroll
            for (int j = 0; j < 5; ++j)
                acc[i][j] = __builtin_amdgcn_mfma_f32_16x16x32_bf16(af[i], bfr[j], acc[i][j], 0, 0, 0);
    }
    #pragma unroll
    for (int i = 0; i < 4; ++i) {
        #pragma unroll
        for (int reg = 0; reg < 4; ++reg) {
            const int o = m0 + i * 16 + quad * 4 + reg;
            const float ph256 = bf2f(Ph[(long)o * PAD + 256]);
            const float s = gamma[o] * rsqrtf(var[o] + 1e-5f);
            const float sv2v = sv2[i * 16 + quad * 4 + reg];
            #pragma unroll
            for (int j = 0; j < 5; ++j) {
                const int c2 = w * 80 + j * 16 + l16;
                const float rtc = bf2f(Rt[(long)c2 * PAD + 256]);
                const float core = acc[i][j][reg] + ph256 * sv1[c2] + (sv2v + ph256 * 4096.0f) * rtc;
                const float val = core * s * NAinv;
                if (c2 < CCH)
                    W5u[((long)b * CCH + o) * CCH + c2] = f2bfu(val + (o == c2 ? 1.0f : 0.0f));
                else if (c2 == CCH)
                    b5[b * CCH + o] = val + s * (qb[o] - mean[o]) + beta[o];
            }
        }
    }
}

// ===== K3: out = W5 @ detect + b5. R3 body verbatim (measured ~42 us). =====
__global__ __launch_bounds__(512) void k_final(const float* __restrict__ D0,
                                               const unsigned short* __restrict__ W5u,
                                               const float* __restrict__ b5,
                                               float* __restrict__ out) {
    const int z = blockIdx.z;
    const int nb = blockIdx.x * 128;
    const float* D = D0 + (long)z * CCH * NDd;
    float* O = out + (long)z * CCH * NDd;
    const unsigned short* W = W5u + (long)z * CCH * CCH;
    const int t = threadIdx.x, wv = t >> 6, lane = t & 63, quad = lane >> 4, l16 = lane & 15;
    const int mw = (wv >> 1) * 64, nw = (wv & 1) * 64;    // 4 m-tiles x 2 n-tiles
    const int r2 = t >> 4, g = t & 15;                    // staging ids (t < 256 only)
    const bool st = (t < 256);
    __shared__ __align__(16) unsigned short lb[2][128][40];

    f32x4 xa[4], xb[4];
    bf16x8 af[2][4], bfr[4];

    auto load_tile = [&](f32x4* x, int kt) {
        const float* base = D + (long)(kt + 2 * r2) * NDd + nb + 8 * g;
        x[0] = *(const f32x4*)(base);
        x[1] = *(const f32x4*)(base + NDd);
        x[2] = *(const f32x4*)(base + 4);
        x[3] = *(const f32x4*)(base + NDd + 4);
    };
    auto write_tile = [&](int buf, const f32x4* x) {
        #pragma unroll
        for (int e2 = 0; e2 < 2; ++e2)
            #pragma unroll
            for (int c = 0; c < 4; ++c) {
                const int n = 8 * g + 4 * e2 + c;
                const int p = ((n & 7) << 4) + (n >> 3);
                const unsigned v = (unsigned)f2bfu(x[2 * e2][c]) |
                                   ((unsigned)f2bfu(x[2 * e2 + 1][c]) << 16);
                *(unsigned*)&lb[buf][p][2 * r2] = v;
            }
    };
    auto loadW = [&](bf16x8* a, int kt) {
        #pragma unroll
        for (int i = 0; i < 4; ++i)
            a[i] = *(const bf16x8*)(W + (long)(mw + i * 16 + l16) * CCH + kt + quad * 8);
    };

    int pj[4];
    #pragma unroll
    for (int j = 0; j < 4; ++j) {
        const int n = nw + j * 16 + l16;
        pj[j] = ((n & 7) << 4) + (n >> 3);
    }

    f32x4 acc[4][4] = {};
    if (st) { load_tile(xa, 0); load_tile(xb, 32); }
    loadW(af[0], 0);
    if (st) { write_tile(0, xa); load_tile(xa, 64); }
    #pragma unroll
    for (int it = 0; it < 8; ++it) {
        __syncthreads();
        const int kt = it * 32;
        #pragma unroll
        for (int j = 0; j < 4; ++j)
            bfr[j] = *(const bf16x8*)&lb[it & 1][pj[j]][quad * 8];
        #pragma unroll
        for (int i = 0; i < 4; ++i)
            #pragma unroll
            for (int j = 0; j < 4; ++j)
                acc[i][j] = __builtin_amdgcn_mfma_f32_16x16x32_bf16(af[it & 1][i], bfr[j], acc[i][j], 0, 0, 0);
        if (it < 7) {
            loadW(af[(it + 1) & 1], kt + 32);
            if (st) {
                write_tile((it + 1) & 1, (it & 1) ? xa : xb);
                if (it < 5) load_tile((it & 1) ? xa : xb, (it + 3) * 32);
            }
        }
    }
    #pragma unroll
    for (int i = 0; i < 4; ++i) {
        float bv[4];
        #pragma unroll
        for (int reg = 0; reg < 4; ++reg)
            bv[reg] = b5[z * CCH + mw + i * 16 + quad * 4 + reg];
        #pragma unroll
        for (int j = 0; j < 4; ++j) {
            const int n = nb + nw + j * 16 + l16;
            #pragma unroll
            for (int reg = 0; reg < 4; ++reg)
                O[(long)(mw + i * 16 + quad * 4 + reg) * NDd + n] = acc[i][j][reg] + bv[reg];
        }
    }
}

extern "C" void kernel_launch(void* const* d_in, const int* in_sizes, int n_in,
                              void* d_out, int out_size, void* d_ws, size_t ws_size,
                              hipStream_t stream) {
    const float* detect = (const float*)d_in[0];
    const float* aim    = (const float*)d_in[1];
    const float* g_w    = (const float*)d_in[2];
    const float* g_b    = (const float*)d_in[3];
    const float* th_w   = (const float*)d_in[4];
    const float* th_b   = (const float*)d_in[5];
    const float* phi_w  = (const float*)d_in[6];
    const float* phi_b  = (const float*)d_in[7];
    const float* q_w    = (const float*)d_in[8];
    const float* q_b    = (const float*)d_in[9];
    const float* gamma  = (const float*)d_in[10];
    const float* beta   = (const float*)d_in[11];
    const float* mean   = (const float*)d_in[12];
    const float* var    = (const float*)d_in[13];
    float* out = (float*)d_out;

    unsigned short* us = (unsigned short*)d_ws;
    unsigned short* Sg      = us;                           // 4*256*256 = 262,144 us
    unsigned short* W5u     = Sg + 262144;                  // 4*256*256 = 262,144 us
    unsigned short* Phat_u  = W5u + 262144;                 // 256*320   =  81,920 us
    unsigned short* RhatT_u = Phat_u + 81920;               // 320*320   = 102,400 us
    float* r  = (float*)(RhatT_u + 102400);                 // 1,024 f
    float* b5 = r + 1024;                                   // 1,024 f   (total ~1.4 MB)

    k1<<<dim3(800), dim3(256), 0, stream>>>(aim, q_w, g_w, g_b, th_w, th_b, phi_w, phi_b,
                                            Sg, r, Phat_u, RhatT_u);
    k2<<<dim3(4, BB), dim3(256), 0, stream>>>(Sg, r, Phat_u, RhatT_u, q_b, gamma, beta,
                                              mean, var, W5u, b5);
    k_final<<<dim3(NDd / 128, 1, BB), dim3(512), 0, stream>>>(detect, W5u, b5, out);
}

// Round 8
// 250.339 us; speedup vs baseline: 1.0035x; 1.0035x over previous
//
#include <hip/hip_runtime.h>

constexpr int BB   = 4;
constexpr int CCH  = 256;
constexpr int IDIM = 128;
constexpr int NAa  = 4096;
constexpr int NDd  = 16384;
constexpr int PAD  = 320;                 // aug dim 257 padded to 320
constexpr float NAinv = 1.0f / 4096.0f;

typedef __bf16 bf16x8 __attribute__((ext_vector_type(8)));
typedef float  f32x4  __attribute__((ext_vector_type(4)));

__device__ inline unsigned short f2bfu(float f) {
    unsigned u = __float_as_uint(f);
    u += 0x7FFFu + ((u >> 16) & 1u);      // RNE
    return (unsigned short)(u >> 16);
}
__device__ inline float bf2f(unsigned short u) {
    return __uint_as_float((unsigned)u << 16);
}
__device__ inline bf16x8 cvt8(f32x4 a, f32x4 b) {
    union { bf16x8 v; unsigned short u[8]; } t;
    t.u[0] = f2bfu(a[0]); t.u[1] = f2bfu(a[1]); t.u[2] = f2bfu(a[2]); t.u[3] = f2bfu(a[3]);
    t.u[4] = f2bfu(b[0]); t.u[5] = f2bfu(b[1]); t.u[6] = f2bfu(b[2]); t.u[7] = f2bfu(b[3]);
    return t.v;
}
// load 8 consecutive f32, convert to a bf16x8 fragment in-register
__device__ inline bf16x8 ld_cvt8(const float* p) {
    return cvt8(*(const f32x4*)p, *(const f32x4*)(p + 4));
}

// ===== K1: 992 independent blocks of 256 =====
//  [0,256):   S f32 partials: (b, 64x64 tile, K-chunk 1024); 4-wave K-split(256) + LDS reduce
//             -> Spart[b][kc][256][256] f32.  256 blocks = 1/CU (R7's 64-block version was
//             latency-bound at 66us: 25% of CUs busy, MfmaUtil 1.1%).
//  [256,272): r rowsums (f32, from aim directly)
//  [272,992): Phat (256x320) / RhatT (320x320) prep — R1 body verbatim
__global__ __launch_bounds__(256) void k1(const float* __restrict__ aim,
                                          const float* __restrict__ qw,
                                          const float* __restrict__ gw,
                                          const float* __restrict__ gb,
                                          const float* __restrict__ thw,
                                          const float* __restrict__ thb,
                                          const float* __restrict__ phw,
                                          const float* __restrict__ phb,
                                          float* __restrict__ Spart,
                                          float* __restrict__ r,
                                          unsigned short* __restrict__ Ph,
                                          unsigned short* __restrict__ Rt) {
    __shared__ __align__(16) char sm[49152];      // S-blocks: 3x4096 f32 reduce buffer
    const int bx = blockIdx.x, t = threadIdx.x;

    if (bx < 256) {
        // ---- S partial tile: b(4) x tile(16) x kc(4) ----
        const int b = bx >> 6, rem = bx & 63;
        const int tile = rem >> 2, kc = rem & 3;
        const int mb = (tile >> 2) * 64, nbb = (tile & 3) * 64;
        const float* A = aim + (long)b * CCH * NAa;
        const int w = t >> 6, lane = t & 63, quad = lane >> 4, l16 = lane & 15;
        f32x4 acc[4][4] = {};
        for (int ks = 0; ks < 8; ++ks) {
            const int k = kc * 1024 + w * 256 + ks * 32 + quad * 8;
            bf16x8 af[4], bfr[4];
            #pragma unroll
            for (int i = 0; i < 4; ++i) af[i]  = ld_cvt8(A + (long)(mb + i * 16 + l16) * NAa + k);
            #pragma unroll
            for (int j = 0; j < 4; ++j) bfr[j] = ld_cvt8(A + (long)(nbb + j * 16 + l16) * NAa + k);
            #pragma unroll
            for (int i = 0; i < 4; ++i)
                #pragma unroll
                for (int j = 0; j < 4; ++j)
                    acc[i][j] = __builtin_amdgcn_mfma_f32_16x16x32_bf16(af[i], bfr[j], acc[i][j], 0, 0, 0);
        }
        float* sred = (float*)sm;                 // 3 x 4096 f32
        if (w > 0) {
            #pragma unroll
            for (int i = 0; i < 4; ++i)
                #pragma unroll
                for (int j = 0; j < 4; ++j)
                    #pragma unroll
                    for (int reg = 0; reg < 4; ++reg)
                        sred[(w - 1) * 4096 + ((i * 4 + j) * 4 + reg) * 64 + lane] = acc[i][j][reg];
        }
        __syncthreads();
        if (w == 0) {
            float* o = Spart + ((long)(b * 4 + kc)) * 65536;
            #pragma unroll
            for (int i = 0; i < 4; ++i)
                #pragma unroll
                for (int j = 0; j < 4; ++j)
                    #pragma unroll
                    for (int reg = 0; reg < 4; ++reg) {
                        float v = acc[i][j][reg];
                        #pragma unroll
                        for (int rg = 0; rg < 3; ++rg)
                            v += sred[rg * 4096 + ((i * 4 + j) * 4 + reg) * 64 + lane];
                        o[(long)(mb + i * 16 + quad * 4 + reg) * 256 + nbb + j * 16 + l16] = v;
                    }
        }
    } else if (bx < 272) {
        // ---- rowsums: 64 rows per block, 16 per wave ----
        const int rid = bx - 256;
        const int w = t >> 6, lane = t & 63;
        for (int rr = 0; rr < 16; ++rr) {
            const int row = rid * 64 + w * 16 + rr;
            const float* src = aim + (long)row * NAa;
            float s = 0.f;
            #pragma unroll 4
            for (int q = 0; q < 16; ++q) {
                f32x4 v = *(const f32x4*)(src + q * 256 + lane * 4);
                s += v[0] + v[1] + v[2] + v[3];
            }
            #pragma unroll
            for (int off = 32; off > 0; off >>= 1) s += __shfl_down(s, off, 64);
            if (lane == 0) r[row] = s;
        }
    } else {
        // ---- prep (R1 k_prep verbatim) ----
        const int idx = (bx - 272) * 256 + t;
        if (idx < CCH * PAD) {
            const int o = idx / PAD, c = idx - o * PAD;
            float acc = 0.f;
            if (c <= 256) {
                for (int i = 0; i < IDIM; ++i)
                    acc += qw[o * IDIM + i] * ((c < 256) ? gw[i * CCH + c] : gb[i]);
            }
            Ph[idx] = f2bfu(acc);
        } else {
            const int id2 = idx - CCH * PAD;
            const int c2 = id2 / PAD, k = id2 - c2 * PAD;   // row c2, col k (transposed)
            float acc = 0.f;
            if (k <= 256 && c2 <= 256) {
                for (int i = 0; i < IDIM; ++i) {
                    const float av = (k < 256) ? thw[i * CCH + k] : thb[i];
                    const float bv = (c2 < 256) ? phw[i * CCH + c2] : phb[i];
                    acc += av * bv;
                }
            }
            Rt[id2] = f2bfu(acc);
        }
    }
}

// ===== K2: 16 blocks (4 m-strips x 4 b), 256 thr. Per strip:
//   M1 = Ph[strip,<256]·S (S = sum of 4 f32 partials, summed+cvt'd in the fragment load;
//   S symmetric -> B-frag reads S rows), M1 -> LDS bf16;
//   W5 = (M1·Rtᵀ + rank-1 aug terms) scaled + I; col 256 -> b5.  =====
__global__ __launch_bounds__(256) void k2(const float* __restrict__ Spart,
                                          const float* __restrict__ r,
                                          const unsigned short* __restrict__ Ph,
                                          const unsigned short* __restrict__ Rt,
                                          const float* __restrict__ qb,
                                          const float* __restrict__ gamma,
                                          const float* __restrict__ beta,
                                          const float* __restrict__ mean,
                                          const float* __restrict__ var,
                                          unsigned short* __restrict__ W5u,
                                          float* __restrict__ b5) {
    const int b = blockIdx.y, m0 = blockIdx.x * 64;
    const float* Sp = Spart + (long)b * 4 * 65536;
    const float* rb = r + b * CCH;
    const int t = threadIdx.x, w = t >> 6, lane = t & 63, quad = lane >> 4, l16 = lane & 15;
    __shared__ __align__(16) unsigned short M1[64][264];   // 33.8 KB, +8 pad -> 4-bank row skew
    __shared__ float sv1[320], sv2[64];

    // step A: sv1[c2] = sum_k<256 r[k]*Rt[c2][k];  sv2[t] = sum_j<256 Ph[m0+t][j]*r[j]
    for (int c2 = t; c2 < 320; c2 += 256) {
        float s = 0.f;
        for (int kk = 0; kk < 256; kk += 4) {
            ushort4 u = *(const ushort4*)(Rt + (long)c2 * PAD + kk);
            s += rb[kk] * bf2f(u.x) + rb[kk + 1] * bf2f(u.y) + rb[kk + 2] * bf2f(u.z) + rb[kk + 3] * bf2f(u.w);
        }
        sv1[c2] = s;
    }
    if (t < 64) {
        const int o = m0 + t;
        float s = 0.f;
        for (int kk = 0; kk < 256; kk += 4) {
            ushort4 u = *(const ushort4*)(Ph + (long)o * PAD + kk);
            s += rb[kk] * bf2f(u.x) + rb[kk + 1] * bf2f(u.y) + rb[kk + 2] * bf2f(u.z) + rb[kk + 3] * bf2f(u.w);
        }
        sv2[t] = s;
    }

    // step B: M1[o][k] = sum_j Ph[o][j]*S[j][k]; wave w owns out-cols w*64..+63
    //         (B = S rows, symmetric; fragment = sum of 4 f32 partials, cvt'd in-register)
    {
        f32x4 acc[4][4] = {};
        for (int jt = 0; jt < 256; jt += 32) {
            bf16x8 af[4], bfr[4];
            #pragma unroll
            for (int i = 0; i < 4; ++i)
                af[i] = *(const bf16x8*)(Ph + (long)(m0 + i * 16 + l16) * PAD + jt + quad * 8);
            #pragma unroll
            for (int j = 0; j < 4; ++j) {
                const int row = w * 64 + j * 16 + l16;
                f32x4 s0 = {}, s1 = {};
                #pragma unroll
                for (int kc = 0; kc < 4; ++kc) {
                    const float* pp = Sp + (long)kc * 65536 + (long)row * 256 + jt + quad * 8;
                    s0 += *(const f32x4*)pp;
                    s1 += *(const f32x4*)(pp + 4);
                }
                bfr[j] = cvt8(s0, s1);
            }
            #pragma unroll
            for (int i = 0; i < 4; ++i)
                #pragma unroll
                for (int j = 0; j < 4; ++j)
                    acc[i][j] = __builtin_amdgcn_mfma_f32_16x16x32_bf16(af[i], bfr[j], acc[i][j], 0, 0, 0);
        }
        #pragma unroll
        for (int i = 0; i < 4; ++i)
            #pragma unroll
            for (int j = 0; j < 4; ++j)
                #pragma unroll
                for (int reg = 0; reg < 4; ++reg)
                    M1[i * 16 + quad * 4 + reg][w * 64 + j * 16 + l16] = f2bfu(acc[i][j][reg]);
    }
    __syncthreads();

    // step C: W5[o][c2] = sum_k M1[o][k]*Rt[c2][k] + aug; wave w owns c2 = w*80..+79
    f32x4 acc[4][5] = {};
    for (int kt = 0; kt < 256; kt += 32) {
        bf16x8 af[4], bfr[5];
        #pragma unroll
        for (int i = 0; i < 4; ++i)
            af[i] = *(const bf16x8*)&M1[i * 16 + l16][kt + quad * 8];
        #pragma unroll
        for (int j = 0; j < 5; ++j)
            bfr[j] = *(const bf16x8*)(Rt + (long)(w * 80 + j * 16 + l16) * PAD + kt + quad * 8);
        #pragma unroll
        for (int i = 0; i < 4; ++i)
            #pragma unroll
            for (int j = 0; j < 5; ++j)
                acc[i][j] = __builtin_amdgcn_mfma_f32_16x16x32_bf16(af[i], bfr[j], acc[i][j], 0, 0, 0);
    }
    #pragma unroll
    for (int i = 0; i < 4; ++i) {
        #pragma unroll
        for (int reg = 0; reg < 4; ++reg) {
            const int o = m0 + i * 16 + quad * 4 + reg;
            const float ph256 = bf2f(Ph[(long)o * PAD + 256]);
            const float s = gamma[o] * rsqrtf(var[o] + 1e-5f);
            const float sv2v = sv2[i * 16 + quad * 4 + reg];
            #pragma unroll
            for (int j = 0; j < 5; ++j) {
                const int c2 = w * 80 + j * 16 + l16;
                const float rtc = bf2f(Rt[(long)c2 * PAD + 256]);
                const float core = acc[i][j][reg] + ph256 * sv1[c2] + (sv2v + ph256 * 4096.0f) * rtc;
                const float val = core * s * NAinv;
                if (c2 < CCH)
                    W5u[((long)b * CCH + o) * CCH + c2] = f2bfu(val + (o == c2 ? 1.0f : 0.0f));
                else if (c2 == CCH)
                    b5[b * CCH + o] = val + s * (qb[o] - mean[o]) + beta[o];
            }
        }
    }
}

// ===== K3: out = W5 @ detect + b5. R3 body verbatim (measured ~42 us). =====
__global__ __launch_bounds__(512) void k_final(const float* __restrict__ D0,
                                               const unsigned short* __restrict__ W5u,
                                               const float* __restrict__ b5,
                                               float* __restrict__ out) {
    const int z = blockIdx.z;
    const int nb = blockIdx.x * 128;
    const float* D = D0 + (long)z * CCH * NDd;
    float* O = out + (long)z * CCH * NDd;
    const unsigned short* W = W5u + (long)z * CCH * CCH;
    const int t = threadIdx.x, wv = t >> 6, lane = t & 63, quad = lane >> 4, l16 = lane & 15;
    const int mw = (wv >> 1) * 64, nw = (wv & 1) * 64;    // 4 m-tiles x 2 n-tiles
    const int r2 = t >> 4, g = t & 15;                    // staging ids (t < 256 only)
    const bool st = (t < 256);
    __shared__ __align__(16) unsigned short lb[2][128][40];

    f32x4 xa[4], xb[4];
    bf16x8 af[2][4], bfr[4];

    auto load_tile = [&](f32x4* x, int kt) {
        const float* base = D + (long)(kt + 2 * r2) * NDd + nb + 8 * g;
        x[0] = *(const f32x4*)(base);
        x[1] = *(const f32x4*)(base + NDd);
        x[2] = *(const f32x4*)(base + 4);
        x[3] = *(const f32x4*)(base + NDd + 4);
    };
    auto write_tile = [&](int buf, const f32x4* x) {
        #pragma unroll
        for (int e2 = 0; e2 < 2; ++e2)
            #pragma unroll
            for (int c = 0; c < 4; ++c) {
                const int n = 8 * g + 4 * e2 + c;
                const int p = ((n & 7) << 4) + (n >> 3);
                const unsigned v = (unsigned)f2bfu(x[2 * e2][c]) |
                                   ((unsigned)f2bfu(x[2 * e2 + 1][c]) << 16);
                *(unsigned*)&lb[buf][p][2 * r2] = v;
            }
    };
    auto loadW = [&](bf16x8* a, int kt) {
        #pragma unroll
        for (int i = 0; i < 4; ++i)
            a[i] = *(const bf16x8*)(W + (long)(mw + i * 16 + l16) * CCH + kt + quad * 8);
    };

    int pj[4];
    #pragma unroll
    for (int j = 0; j < 4; ++j) {
        const int n = nw + j * 16 + l16;
        pj[j] = ((n & 7) << 4) + (n >> 3);
    }

    f32x4 acc[4][4] = {};
    if (st) { load_tile(xa, 0); load_tile(xb, 32); }
    loadW(af[0], 0);
    if (st) { write_tile(0, xa); load_tile(xa, 64); }
    #pragma unroll
    for (int it = 0; it < 8; ++it) {
        __syncthreads();
        const int kt = it * 32;
        #pragma unroll
        for (int j = 0; j < 4; ++j)
            bfr[j] = *(const bf16x8*)&lb[it & 1][pj[j]][quad * 8];
        #pragma unroll
        for (int i = 0; i < 4; ++i)
            #pragma unroll
            for (int j = 0; j < 4; ++j)
                acc[i][j] = __builtin_amdgcn_mfma_f32_16x16x32_bf16(af[it & 1][i], bfr[j], acc[i][j], 0, 0, 0);
        if (it < 7) {
            loadW(af[(it + 1) & 1], kt + 32);
            if (st) {
                write_tile((it + 1) & 1, (it & 1) ? xa : xb);
                if (it < 5) load_tile((it & 1) ? xa : xb, (it + 3) * 32);
            }
        }
    }
    #pragma unroll
    for (int i = 0; i < 4; ++i) {
        float bv[4];
        #pragma unroll
        for (int reg = 0; reg < 4; ++reg)
            bv[reg] = b5[z * CCH + mw + i * 16 + quad * 4 + reg];
        #pragma unroll
        for (int j = 0; j < 4; ++j) {
            const int n = nb + nw + j * 16 + l16;
            #pragma unroll
            for (int reg = 0; reg < 4; ++reg)
                O[(long)(mw + i * 16 + quad * 4 + reg) * NDd + n] = acc[i][j][reg] + bv[reg];
        }
    }
}

extern "C" void kernel_launch(void* const* d_in, const int* in_sizes, int n_in,
                              void* d_out, int out_size, void* d_ws, size_t ws_size,
                              hipStream_t stream) {
    const float* detect = (const float*)d_in[0];
    const float* aim    = (const float*)d_in[1];
    const float* g_w    = (const float*)d_in[2];
    const float* g_b    = (const float*)d_in[3];
    const float* th_w   = (const float*)d_in[4];
    const float* th_b   = (const float*)d_in[5];
    const float* phi_w  = (const float*)d_in[6];
    const float* phi_b  = (const float*)d_in[7];
    const float* q_w    = (const float*)d_in[8];
    const float* q_b    = (const float*)d_in[9];
    const float* gamma  = (const float*)d_in[10];
    const float* beta   = (const float*)d_in[11];
    const float* mean   = (const float*)d_in[12];
    const float* var    = (const float*)d_in[13];
    float* out = (float*)d_out;

    float* ws = (float*)d_ws;
    float* Spart = ws;                                      // 4*4*65536 = 1,048,576 f (4 MB)
    unsigned short* us = (unsigned short*)(Spart + 1048576);
    unsigned short* W5u     = us;                           // 4*256*256 = 262,144 us
    unsigned short* Phat_u  = W5u + 262144;                 // 256*320   =  81,920 us
    unsigned short* RhatT_u = Phat_u + 81920;               // 320*320   = 102,400 us
    float* r  = (float*)(RhatT_u + 102400);                 // 1,024 f
    float* b5 = r + 1024;                                   // 1,024 f   (total ~5 MB)

    k1<<<dim3(992), dim3(256), 0, stream>>>(aim, q_w, g_w, g_b, th_w, th_b, phi_w, phi_b,
                                            Spart, r, Phat_u, RhatT_u);
    k2<<<dim3(4, BB), dim3(256), 0, stream>>>(Spart, r, Phat_u, RhatT_u, q_b, gamma, beta,
                                              mean, var, W5u, b5);
    k_final<<<dim3(NDd / 128, 1, BB), dim3(512), 0, stream>>>(detect, W5u, b5, out);
}

// Round 9
// 220.926 us; speedup vs baseline: 1.1371x; 1.1331x over previous
//
#include <hip/hip_runtime.h>

constexpr int BB   = 4;
constexpr int CCH  = 256;
constexpr int IDIM = 128;
constexpr int NAa  = 4096;
constexpr int NDd  = 16384;
constexpr int PAD  = 320;                 // aug dim 257 padded to 320
constexpr float NAinv = 1.0f / 4096.0f;

typedef __bf16 bf16x8 __attribute__((ext_vector_type(8)));
typedef float  f32x4  __attribute__((ext_vector_type(4)));

__device__ inline unsigned short f2bfu(float f) {
    unsigned u = __float_as_uint(f);
    u += 0x7FFFu + ((u >> 16) & 1u);      // RNE
    return (unsigned short)(u >> 16);
}
__device__ inline float bf2f(unsigned short u) {
    return __uint_as_float((unsigned)u << 16);
}
__device__ inline bf16x8 cvt8(f32x4 a, f32x4 b) {
    union { bf16x8 v; unsigned short u[8]; } t;
    t.u[0] = f2bfu(a[0]); t.u[1] = f2bfu(a[1]); t.u[2] = f2bfu(a[2]); t.u[3] = f2bfu(a[3]);
    t.u[4] = f2bfu(b[0]); t.u[5] = f2bfu(b[1]); t.u[6] = f2bfu(b[2]); t.u[7] = f2bfu(b[3]);
    return t.v;
}
// load 8 consecutive f32, convert to a bf16x8 fragment in-register
__device__ inline bf16x8 ld_cvt8(const float* p) {
    return cvt8(*(const f32x4*)p, *(const f32x4*)(p + 4));
}

// ===== K1 (R8 verbatim): 992 independent blocks of 256 =====
//  [0,256):   S f32 partials -> Spart[b][kc][256][256]
//  [256,272): r rowsums
//  [272,992): Phat / RhatT prep
__global__ __launch_bounds__(256) void k1(const float* __restrict__ aim,
                                          const float* __restrict__ qw,
                                          const float* __restrict__ gw,
                                          const float* __restrict__ gb,
                                          const float* __restrict__ thw,
                                          const float* __restrict__ thb,
                                          const float* __restrict__ phw,
                                          const float* __restrict__ phb,
                                          float* __restrict__ Spart,
                                          float* __restrict__ r,
                                          unsigned short* __restrict__ Ph,
                                          unsigned short* __restrict__ Rt) {
    __shared__ __align__(16) char sm[49152];      // S-blocks: 3x4096 f32 reduce buffer
    const int bx = blockIdx.x, t = threadIdx.x;

    if (bx < 256) {
        const int b = bx >> 6, rem = bx & 63;
        const int tile = rem >> 2, kc = rem & 3;
        const int mb = (tile >> 2) * 64, nbb = (tile & 3) * 64;
        const float* A = aim + (long)b * CCH * NAa;
        const int w = t >> 6, lane = t & 63, quad = lane >> 4, l16 = lane & 15;
        f32x4 acc[4][4] = {};
        for (int ks = 0; ks < 8; ++ks) {
            const int k = kc * 1024 + w * 256 + ks * 32 + quad * 8;
            bf16x8 af[4], bfr[4];
            #pragma unroll
            for (int i = 0; i < 4; ++i) af[i]  = ld_cvt8(A + (long)(mb + i * 16 + l16) * NAa + k);
            #pragma unroll
            for (int j = 0; j < 4; ++j) bfr[j] = ld_cvt8(A + (long)(nbb + j * 16 + l16) * NAa + k);
            #pragma unroll
            for (int i = 0; i < 4; ++i)
                #pragma unroll
                for (int j = 0; j < 4; ++j)
                    acc[i][j] = __builtin_amdgcn_mfma_f32_16x16x32_bf16(af[i], bfr[j], acc[i][j], 0, 0, 0);
        }
        float* sred = (float*)sm;                 // 3 x 4096 f32
        if (w > 0) {
            #pragma unroll
            for (int i = 0; i < 4; ++i)
                #pragma unroll
                for (int j = 0; j < 4; ++j)
                    #pragma unroll
                    for (int reg = 0; reg < 4; ++reg)
                        sred[(w - 1) * 4096 + ((i * 4 + j) * 4 + reg) * 64 + lane] = acc[i][j][reg];
        }
        __syncthreads();
        if (w == 0) {
            float* o = Spart + ((long)(b * 4 + kc)) * 65536;
            #pragma unroll
            for (int i = 0; i < 4; ++i)
                #pragma unroll
                for (int j = 0; j < 4; ++j)
                    #pragma unroll
                    for (int reg = 0; reg < 4; ++reg) {
                        float v = acc[i][j][reg];
                        #pragma unroll
                        for (int rg = 0; rg < 3; ++rg)
                            v += sred[rg * 4096 + ((i * 4 + j) * 4 + reg) * 64 + lane];
                        o[(long)(mb + i * 16 + quad * 4 + reg) * 256 + nbb + j * 16 + l16] = v;
                    }
        }
    } else if (bx < 272) {
        const int rid = bx - 256;
        const int w = t >> 6, lane = t & 63;
        for (int rr = 0; rr < 16; ++rr) {
            const int row = rid * 64 + w * 16 + rr;
            const float* src = aim + (long)row * NAa;
            float s = 0.f;
            #pragma unroll 4
            for (int q = 0; q < 16; ++q) {
                f32x4 v = *(const f32x4*)(src + q * 256 + lane * 4);
                s += v[0] + v[1] + v[2] + v[3];
            }
            #pragma unroll
            for (int off = 32; off > 0; off >>= 1) s += __shfl_down(s, off, 64);
            if (lane == 0) r[row] = s;
        }
    } else {
        const int idx = (bx - 272) * 256 + t;
        if (idx < CCH * PAD) {
            const int o = idx / PAD, c = idx - o * PAD;
            float acc = 0.f;
            if (c <= 256) {
                for (int i = 0; i < IDIM; ++i)
                    acc += qw[o * IDIM + i] * ((c < 256) ? gw[i * CCH + c] : gb[i]);
            }
            Ph[idx] = f2bfu(acc);
        } else {
            const int id2 = idx - CCH * PAD;
            const int c2 = id2 / PAD, k = id2 - c2 * PAD;   // row c2, col k (transposed)
            float acc = 0.f;
            if (k <= 256 && c2 <= 256) {
                for (int i = 0; i < IDIM; ++i) {
                    const float av = (k < 256) ? thw[i * CCH + k] : thb[i];
                    const float bv = (c2 < 256) ? phw[i * CCH + c2] : phb[i];
                    acc += av * bv;
                }
            }
            Rt[id2] = f2bfu(acc);
        }
    }
}

// ===== K2a: 68 blocks of 256. R8's k2 was 16 blocks / 59us (Occ 0.67%, latency-bound).
//  [0,64):  M1 = Ph·S tile (64x64 out, 4-wave j-split K=256 + LDS reduce);
//           S fragment = sum of 4 f32 Spart partials, cvt'd in-register (R8 scheme).
//  [64,68): aug vectors sv1[b][c2] = r·Rt[c2,:256], sv2[b][o] = Ph[o,:256]·r  =====
__global__ __launch_bounds__(256) void k2a(const float* __restrict__ Spart,
                                           const float* __restrict__ r,
                                           const unsigned short* __restrict__ Ph,
                                           const unsigned short* __restrict__ Rt,
                                           unsigned short* __restrict__ M1g,
                                           float* __restrict__ sv1,
                                           float* __restrict__ sv2) {
    __shared__ __align__(16) float sred[3 * 4096];   // 48 KB
    const int bx = blockIdx.x, t = threadIdx.x;

    if (bx < 64) {
        const int b = bx >> 4, rem = bx & 15;
        const int m0 = (rem >> 2) * 64, n0 = (rem & 3) * 64;
        const float* Sp = Spart + (long)b * 4 * 65536;
        const int w = t >> 6, lane = t & 63, quad = lane >> 4, l16 = lane & 15;
        f32x4 acc[4][4] = {};
        #pragma unroll
        for (int js = 0; js < 2; ++js) {
            const int jt = w * 64 + js * 32;
            bf16x8 af[4], bfr[4];
            #pragma unroll
            for (int i = 0; i < 4; ++i)
                af[i] = *(const bf16x8*)(Ph + (long)(m0 + i * 16 + l16) * PAD + jt + quad * 8);
            #pragma unroll
            for (int j = 0; j < 4; ++j) {
                const int row = n0 + j * 16 + l16;            // S row (symmetric)
                f32x4 s0 = {}, s1 = {};
                #pragma unroll
                for (int kc = 0; kc < 4; ++kc) {
                    const float* pp = Sp + (long)kc * 65536 + (long)row * 256 + jt + quad * 8;
                    s0 += *(const f32x4*)pp;
                    s1 += *(const f32x4*)(pp + 4);
                }
                bfr[j] = cvt8(s0, s1);
            }
            #pragma unroll
            for (int i = 0; i < 4; ++i)
                #pragma unroll
                for (int j = 0; j < 4; ++j)
                    acc[i][j] = __builtin_amdgcn_mfma_f32_16x16x32_bf16(af[i], bfr[j], acc[i][j], 0, 0, 0);
        }
        if (w > 0) {
            #pragma unroll
            for (int i = 0; i < 4; ++i)
                #pragma unroll
                for (int j = 0; j < 4; ++j)
                    #pragma unroll
                    for (int reg = 0; reg < 4; ++reg)
                        sred[(w - 1) * 4096 + ((i * 4 + j) * 4 + reg) * 64 + lane] = acc[i][j][reg];
        }
        __syncthreads();
        if (w == 0) {
            unsigned short* M = M1g + (long)b * 65536;
            #pragma unroll
            for (int i = 0; i < 4; ++i)
                #pragma unroll
                for (int j = 0; j < 4; ++j)
                    #pragma unroll
                    for (int reg = 0; reg < 4; ++reg) {
                        float v = acc[i][j][reg];
                        #pragma unroll
                        for (int rg = 0; rg < 3; ++rg)
                            v += sred[rg * 4096 + ((i * 4 + j) * 4 + reg) * 64 + lane];
                        M[(long)(m0 + i * 16 + quad * 4 + reg) * 256 + n0 + j * 16 + l16] = f2bfu(v);
                    }
        }
    } else {
        const int b = bx - 64;
        const float* rb = r + b * CCH;
        for (int c2 = t; c2 < 320; c2 += 256) {
            float s = 0.f;
            for (int kk = 0; kk < 256; kk += 4) {
                ushort4 u = *(const ushort4*)(Rt + (long)c2 * PAD + kk);
                s += rb[kk] * bf2f(u.x) + rb[kk + 1] * bf2f(u.y) + rb[kk + 2] * bf2f(u.z) + rb[kk + 3] * bf2f(u.w);
            }
            sv1[b * 320 + c2] = s;
        }
        {
            const int o = t;
            float s = 0.f;
            for (int kk = 0; kk < 256; kk += 4) {
                ushort4 u = *(const ushort4*)(Ph + (long)o * PAD + kk);
                s += rb[kk] * bf2f(u.x) + rb[kk + 1] * bf2f(u.y) + rb[kk + 2] * bf2f(u.z) + rb[kk + 3] * bf2f(u.w);
            }
            sv2[b * 256 + o] = s;
        }
    }
}

// ===== K2b: W5 = (M1·Rtᵀ + rank-1 aug) scaled + I ; col 256 -> b5.
//  grid (5 n-strips, 4 m-strips, BB), 256 thr: 80 blocks, 4-wave K-split(256) + LDS reduce. =====
__global__ __launch_bounds__(256) void k2b(const unsigned short* __restrict__ M1g,
                                           const float* __restrict__ sv1,
                                           const float* __restrict__ sv2,
                                           const unsigned short* __restrict__ Ph,
                                           const unsigned short* __restrict__ Rt,
                                           const float* __restrict__ qb,
                                           const float* __restrict__ gamma,
                                           const float* __restrict__ beta,
                                           const float* __restrict__ mean,
                                           const float* __restrict__ var,
                                           unsigned short* __restrict__ W5u,
                                           float* __restrict__ b5) {
    __shared__ __align__(16) float sred[3 * 4096];   // 48 KB
    const int b = blockIdx.z, m0 = blockIdx.y * 64, n0 = blockIdx.x * 64;
    const unsigned short* M = M1g + (long)b * 65536;
    const int t = threadIdx.x, w = t >> 6, lane = t & 63, quad = lane >> 4, l16 = lane & 15;

    f32x4 acc[4][4] = {};
    #pragma unroll
    for (int ks = 0; ks < 2; ++ks) {
        const int kt = w * 64 + ks * 32;
        bf16x8 af[4], bfr[4];
        #pragma unroll
        for (int i = 0; i < 4; ++i)
            af[i] = *(const bf16x8*)(M + (long)(m0 + i * 16 + l16) * 256 + kt + quad * 8);
        #pragma unroll
        for (int j = 0; j < 4; ++j)
            bfr[j] = *(const bf16x8*)(Rt + (long)(n0 + j * 16 + l16) * PAD + kt + quad * 8);
        #pragma unroll
        for (int i = 0; i < 4; ++i)
            #pragma unroll
            for (int j = 0; j < 4; ++j)
                acc[i][j] = __builtin_amdgcn_mfma_f32_16x16x32_bf16(af[i], bfr[j], acc[i][j], 0, 0, 0);
    }
    if (w > 0) {
        #pragma unroll
        for (int i = 0; i < 4; ++i)
            #pragma unroll
            for (int j = 0; j < 4; ++j)
                #pragma unroll
                for (int reg = 0; reg < 4; ++reg)
                    sred[(w - 1) * 4096 + ((i * 4 + j) * 4 + reg) * 64 + lane] = acc[i][j][reg];
    }
    __syncthreads();
    if (w == 0) {
        #pragma unroll
        for (int i = 0; i < 4; ++i) {
            #pragma unroll
            for (int reg = 0; reg < 4; ++reg) {
                const int o = m0 + i * 16 + quad * 4 + reg;
                const float ph256 = bf2f(Ph[(long)o * PAD + 256]);
                const float s = gamma[o] * rsqrtf(var[o] + 1e-5f);
                const float sv2v = sv2[b * 256 + o];
                #pragma unroll
                for (int j = 0; j < 4; ++j) {
                    const int c2 = n0 + j * 16 + l16;
                    float v = acc[i][j][reg];
                    #pragma unroll
                    for (int rg = 0; rg < 3; ++rg)
                        v += sred[rg * 4096 + ((i * 4 + j) * 4 + reg) * 64 + lane];
                    const float rtc = bf2f(Rt[(long)c2 * PAD + 256]);
                    const float core = v + ph256 * sv1[b * 320 + c2] + (sv2v + ph256 * 4096.0f) * rtc;
                    const float val = core * s * NAinv;
                    if (c2 < CCH)
                        W5u[((long)b * CCH + o) * CCH + c2] = f2bfu(val + (o == c2 ? 1.0f : 0.0f));
                    else if (c2 == CCH)
                        b5[b * CCH + o] = val + s * (qb[o] - mean[o]) + beta[o];
                }
            }
        }
    }
}

// ===== K3: out = W5 @ detect + b5. R3 body verbatim (measured ~42 us). =====
__global__ __launch_bounds__(512) void k_final(const float* __restrict__ D0,
                                               const unsigned short* __restrict__ W5u,
                                               const float* __restrict__ b5,
                                               float* __restrict__ out) {
    const int z = blockIdx.z;
    const int nb = blockIdx.x * 128;
    const float* D = D0 + (long)z * CCH * NDd;
    float* O = out + (long)z * CCH * NDd;
    const unsigned short* W = W5u + (long)z * CCH * CCH;
    const int t = threadIdx.x, wv = t >> 6, lane = t & 63, quad = lane >> 4, l16 = lane & 15;
    const int mw = (wv >> 1) * 64, nw = (wv & 1) * 64;    // 4 m-tiles x 2 n-tiles
    const int r2 = t >> 4, g = t & 15;                    // staging ids (t < 256 only)
    const bool st = (t < 256);
    __shared__ __align__(16) unsigned short lb[2][128][40];

    f32x4 xa[4], xb[4];
    bf16x8 af[2][4], bfr[4];

    auto load_tile = [&](f32x4* x, int kt) {
        const float* base = D + (long)(kt + 2 * r2) * NDd + nb + 8 * g;
        x[0] = *(const f32x4*)(base);
        x[1] = *(const f32x4*)(base + NDd);
        x[2] = *(const f32x4*)(base + 4);
        x[3] = *(const f32x4*)(base + NDd + 4);
    };
    auto write_tile = [&](int buf, const f32x4* x) {
        #pragma unroll
        for (int e2 = 0; e2 < 2; ++e2)
            #pragma unroll
            for (int c = 0; c < 4; ++c) {
                const int n = 8 * g + 4 * e2 + c;
                const int p = ((n & 7) << 4) + (n >> 3);
                const unsigned v = (unsigned)f2bfu(x[2 * e2][c]) |
                                   ((unsigned)f2bfu(x[2 * e2 + 1][c]) << 16);
                *(unsigned*)&lb[buf][p][2 * r2] = v;
            }
    };
    auto loadW = [&](bf16x8* a, int kt) {
        #pragma unroll
        for (int i = 0; i < 4; ++i)
            a[i] = *(const bf16x8*)(W + (long)(mw + i * 16 + l16) * CCH + kt + quad * 8);
    };

    int pj[4];
    #pragma unroll
    for (int j = 0; j < 4; ++j) {
        const int n = nw + j * 16 + l16;
        pj[j] = ((n & 7) << 4) + (n >> 3);
    }

    f32x4 acc[4][4] = {};
    if (st) { load_tile(xa, 0); load_tile(xb, 32); }
    loadW(af[0], 0);
    if (st) { write_tile(0, xa); load_tile(xa, 64); }
    #pragma unroll
    for (int it = 0; it < 8; ++it) {
        __syncthreads();
        const int kt = it * 32;
        #pragma unroll
        for (int j = 0; j < 4; ++j)
            bfr[j] = *(const bf16x8*)&lb[it & 1][pj[j]][quad * 8];
        #pragma unroll
        for (int i = 0; i < 4; ++i)
            #pragma unroll
            for (int j = 0; j < 4; ++j)
                acc[i][j] = __builtin_amdgcn_mfma_f32_16x16x32_bf16(af[it & 1][i], bfr[j], acc[i][j], 0, 0, 0);
        if (it < 7) {
            loadW(af[(it + 1) & 1], kt + 32);
            if (st) {
                write_tile((it + 1) & 1, (it & 1) ? xa : xb);
                if (it < 5) load_tile((it & 1) ? xa : xb, (it + 3) * 32);
            }
        }
    }
    #pragma unroll
    for (int i = 0; i < 4; ++i) {
        float bv[4];
        #pragma unroll
        for (int reg = 0; reg < 4; ++reg)
            bv[reg] = b5[z * CCH + mw + i * 16 + quad * 4 + reg];
        #pragma unroll
        for (int j = 0; j < 4; ++j) {
            const int n = nb + nw + j * 16 + l16;
            #pragma unroll
            for (int reg = 0; reg < 4; ++reg)
                O[(long)(mw + i * 16 + quad * 4 + reg) * NDd + n] = acc[i][j][reg] + bv[reg];
        }
    }
}

extern "C" void kernel_launch(void* const* d_in, const int* in_sizes, int n_in,
                              void* d_out, int out_size, void* d_ws, size_t ws_size,
                              hipStream_t stream) {
    const float* detect = (const float*)d_in[0];
    const float* aim    = (const float*)d_in[1];
    const float* g_w    = (const float*)d_in[2];
    const float* g_b    = (const float*)d_in[3];
    const float* th_w   = (const float*)d_in[4];
    const float* th_b   = (const float*)d_in[5];
    const float* phi_w  = (const float*)d_in[6];
    const float* phi_b  = (const float*)d_in[7];
    const float* q_w    = (const float*)d_in[8];
    const float* q_b    = (const float*)d_in[9];
    const float* gamma  = (const float*)d_in[10];
    const float* beta   = (const float*)d_in[11];
    const float* mean   = (const float*)d_in[12];
    const float* var    = (const float*)d_in[13];
    float* out = (float*)d_out;

    float* ws = (float*)d_ws;
    float* Spart = ws;                                      // 4*4*65536 = 1,048,576 f (4 MB)
    unsigned short* us = (unsigned short*)(Spart + 1048576);
    unsigned short* W5u     = us;                           // 4*256*256 = 262,144 us
    unsigned short* Phat_u  = W5u + 262144;                 // 256*320   =  81,920 us
    unsigned short* RhatT_u = Phat_u + 81920;               // 320*320   = 102,400 us
    unsigned short* M1g     = RhatT_u + 102400;             // 4*256*256 = 262,144 us
    float* r   = (float*)(M1g + 262144);                    // 1,024 f
    float* b5  = r + 1024;                                  // 1,024 f
    float* sv1 = b5 + 1024;                                 // 1,280 f
    float* sv2 = sv1 + 1280;                                // 1,024 f  (total ~5.6 MB)

    k1<<<dim3(992), dim3(256), 0, stream>>>(aim, q_w, g_w, g_b, th_w, th_b, phi_w, phi_b,
                                            Spart, r, Phat_u, RhatT_u);
    k2a<<<dim3(68), dim3(256), 0, stream>>>(Spart, r, Phat_u, RhatT_u, M1g, sv1, sv2);
    k2b<<<dim3(5, 4, BB), dim3(256), 0, stream>>>(M1g, sv1, sv2, Phat_u, RhatT_u, q_b,
                                                  gamma, beta, mean, var, W5u, b5);
    k_final<<<dim3(NDd / 128, 1, BB), dim3(512), 0, stream>>>(detect, W5u, b5, out);
}